// Round 8
// baseline (138.290 us; speedup 1.0000x reference)
//
#include <hip/hip_runtime.h>
#include <hip/hip_bf16.h>

// DiffAlphaSplitModel: VOCAB=64, H=64, HALF=32, B=256, L=2048.
//  1) 64 distinct tokens -> per-vocab tables: k (normalized), h (raw),
//     Gram G[v][w] = k_v . k_w per chain.
//  2) r = M_L q via backward recurrence, CHUNKED (T=32):
//       d_q = g_q - sum_{ps>q} c_ps G[t_q][t_ps] d_ps   (triangular solve)
//  3) DUAL-SPACE state: gf_v = k_v . u for all 64 vocab (lane = v);
//     r accumulated in vocab space (w_v), applied to h once at the end.
//  4) THIS ROUND: true software pipeline.
//     - bpermute moved OFF the serial chain: g_next = bperm(gf_pre, tq_next)
//       issued at body start, corrected post-solve with Gx[q] =
//       G[tq_next][ta_cur[q]] (exact reassociation).
//     - aW for chunk ci+1 gathered during chunk ci's solve (double-banked).
//     - tokens double-banked (loaded 2 chunks ahead) so no gather address
//       ever waits on a token read.
//     - solve reads ONLY registers (aW_cur, gq_cur): zero LDS waits on the
//       critical path; the ~105 DS ops/chunk complete under the solve.
//  s-chain and e-chain in separate waves (block=128). No barriers/LDS writes
//  in the main loop.
//
// ws layout (floats):
//   [0     ..  4095] compact k [2][64][32]
//   [4096  ..  8191] compact h [2][64][32]
//   [16384 .. 24575] Gram [2][64][64]
//   [24576 .. 40959] rbuf [256][64]

#define L_SEQ 2048
#define NPOS  2047
#define TCH   32
#define NCH   64

__device__ __forceinline__ float rdlane(float v, int l) {
    return __int_as_float(__builtin_amdgcn_readlane(__float_as_int(v), l));
}

// ---------------- Kernel A: per-vocab tables -------------------------------
__global__ void build_tables(const float* __restrict__ embed,
                             const float* __restrict__ w1, const float* __restrict__ b1,
                             const float* __restrict__ w2, const float* __restrict__ b2,
                             const float* __restrict__ ln_g, const float* __restrict__ ln_b,
                             const float* __restrict__ ws, const float* __restrict__ bs,
                             const float* __restrict__ we, const float* __restrict__ be,
                             float* __restrict__ tabs) {
    const int v = blockIdx.x;
    const int t = threadIdx.x;        // 0..63
    __shared__ float sh_h[64];
    __shared__ float sh_a[128];
    __shared__ float sh_x[64];

    sh_h[t] = embed[v * 64 + t];
    __syncthreads();

    float acc0 = b1[t], acc1 = b1[t + 64];
    #pragma unroll 8
    for (int k = 0; k < 64; ++k) {
        const float hv = sh_h[k];
        acc0 += hv * w1[k * 128 + t];
        acc1 += hv * w1[k * 128 + t + 64];
    }
    sh_a[t]      = fmaxf(acc0, 0.f);
    sh_a[t + 64] = fmaxf(acc1, 0.f);
    __syncthreads();

    float x = sh_h[t] + b2[t];
    #pragma unroll 8
    for (int k = 0; k < 128; ++k) x += sh_a[k] * w2[k * 64 + t];

    float mu = x;
    for (int m = 1; m <= 32; m <<= 1) mu += __shfl_xor(mu, m);
    mu *= (1.f / 64.f);
    const float dx = x - mu;
    float var = dx * dx;
    for (int m = 1; m <= 32; m <<= 1) var += __shfl_xor(var, m);
    var *= (1.f / 64.f);
    const float hln = dx * rsqrtf(var + 1e-5f) * ln_g[t] + ln_b[t];
    sh_x[t] = hln;
    __syncthreads();

    const int j   = t & 31;
    const int mem = t >> 5;
    const float* W  = mem ? we : ws;
    const float* Bv = mem ? be : bs;
    float p = Bv[j];
    #pragma unroll 8
    for (int k = 0; k < 64; ++k) p += sh_x[k] * W[k * 32 + j];

    float nn = p * p;
    for (int m = 1; m <= 16; m <<= 1) nn += __shfl_xor(nn, m);
    const float kn = p / fmaxf(sqrtf(nn), 1e-12f);

    tabs[(mem * 64 + v) * 32 + j]        = kn;   // normalized key
    tabs[4096 + (mem * 64 + v) * 32 + j] = p;    // raw projection
}

// ---------------- Kernel A2: Gram tables -----------------------------------
__global__ void gram_kernel(const float* __restrict__ tabs, float* __restrict__ gout) {
    const int v  = blockIdx.x;
    const int tt = threadIdx.x;          // 0..127
    const int m  = tt >> 6, w = tt & 63;
    __shared__ float kv[64];
    if (tt < 64) kv[tt] = tabs[((tt >> 5) * 64 + v) * 32 + (tt & 31)];
    __syncthreads();
    const float* kw  = &tabs[(m * 64 + w) * 32];
    const float* kvm = &kv[m * 32];
    float acc = 0.f;
    #pragma unroll 8
    for (int j = 0; j < 32; ++j) acc += kvm[j] * kw[j];
    gout[m * 4096 + v * 64 + w] = acc;
}

// ======== pipelined-body macros (all static indexing) =======================
// Tokens for chunk CN -> packed PK[8] (4 tokens/int, 8b each) + per-lane TQ.
#define LOADTOK(CN, PK, TQ)                                                   \
  do {                                                                        \
    const int t0_ = NPOS - TCH * ((CN) + 1);                                  \
    const int4* tp_ = (const int4*)&seq_sh[t0_];                              \
    _Pragma("unroll")                                                         \
    for (int k2 = 0; k2 < 8; ++k2) {                                          \
      int4 v_ = tp_[k2];                                                      \
      PK[k2] = v_.x | (v_.y << 8) | (v_.z << 16) | (v_.w << 24);              \
    }                                                                         \
    TQ = seq_sh[t0_ + q];                                                     \
  } while (0)

// aW for chunk CN (row = TQ of that chunk, cols = its own tokens PK)
#define PREPAW(CN, PK, TQ, AW)                                                \
  do {                                                                        \
    const int t0_ = NPOS - TCH * ((CN) + 1);                                  \
    const float* rowQ_ = &gt[mBase + (TQ) * 65];                              \
    const float cfb_ = mF ? (float)(t0_ + 1) * invL : 1.0f;                   \
    _Pragma("unroll")                                                         \
    for (int ps = 1; ps < TCH; ++ps) {                                        \
      const int tk_ = (PK[ps >> 2] >> ((ps & 3) * 8)) & 63;                   \
      const float gv_ = rowQ_[tk_];                                           \
      const float cf_ = cfb_ + (float)ps * cfs;                               \
      AW[ps] = (q < ps) ? cf_ * gv_ : 0.f;                                    \
    }                                                                         \
  } while (0)

// One chunk: cur banks {PKC,TQC,AWC,GQC}, next banks {PKN,TQN,AWN,GQN(out)}.
#define BODY(CI, PKC, TQC, AWC, GQC, PKN, TQN, AWN, GQN)                      \
  do {                                                                        \
    /* issue: bperm for next chunk (uses PRE-update gf) */                    \
    const int bpN_ = __builtin_amdgcn_ds_bpermute((TQN) << 2,                 \
                                                  __float_as_int(gf));        \
    /* issue: aW for next chunk */                                            \
    PREPAW((CI) + 1, PKN, TQN, AWN);                                          \
    /* unpack cur tokens once (shared by Gx, Gc, w-mask) */                   \
    int tl_[TCH];                                                             \
    _Pragma("unroll")                                                         \
    for (int qq = 0; qq < TCH; ++qq)                                          \
      tl_[qq] = (PKC[qq >> 2] >> ((qq & 3) * 8)) & 63;                        \
    /* issue: Gx (row tq_next, cols cur tokens) and Gc (row lane) */          \
    float Gx_[TCH], Gc_[TCH];                                                 \
    {                                                                         \
      const float* rowN_ = &gt[mBase + (TQN) * 65];                           \
      const float* rowV_ = &gt[rowV];                                         \
      _Pragma("unroll")                                                       \
      for (int qq = 0; qq < TCH; ++qq) {                                      \
        Gx_[qq] = rowN_[tl_[qq]];                                             \
        Gc_[qq] = rowV_[tl_[qq]];                                             \
      }                                                                       \
    }                                                                         \
    /* issue: tokens 2 chunks ahead -> overwrite cur bank */                  \
    {                                                                         \
      const int cn_ = ((CI) + 2 < NCH) ? (CI) + 2 : NCH - 1;                  \
      LOADTOK(cn_, PKC, TQC);                                                 \
    }                                                                         \
    __builtin_amdgcn_sched_barrier(0);                                        \
    /* solve: registers only, no LDS waits */                                 \
    float dv_ = (GQC);                                                        \
    _Pragma("unroll")                                                         \
    for (int ps = TCH - 1; ps >= 1; --ps)                                     \
      dv_ = fmaf(-AWC[ps], rdlane(dv_, ps), dv_);                             \
    const int   pq_ = NPOS - TCH * ((CI) + 1) + q;                            \
    const float cq_ = mF ? (float)(pq_ + 1) * invL : 1.0f;                    \
    const float ev_ = (pq_ >= 0) ? cq_ * dv_ : 0.f;                           \
    /* updates: gf, w, and corrected gq_next */                               \
    float gA_=0.f, gB_=0.f, wA_=0.f, wB_=0.f, cA_=0.f, cB_=0.f;               \
    _Pragma("unroll")                                                         \
    for (int qq = 0; qq < TCH; qq += 2) {                                     \
      const float e0_ = rdlane(ev_, qq);                                      \
      const float e1_ = rdlane(ev_, qq + 1);                                  \
      gA_ = fmaf(e0_, Gc_[qq],     gA_);                                      \
      gB_ = fmaf(e1_, Gc_[qq + 1], gB_);                                      \
      cA_ = fmaf(e0_, Gx_[qq],     cA_);                                      \
      cB_ = fmaf(e1_, Gx_[qq + 1], cB_);                                      \
      wA_ += (lane == tl_[qq])     ? e0_ : 0.f;                               \
      wB_ += (lane == tl_[qq + 1]) ? e1_ : 0.f;                               \
    }                                                                         \
    gf -= gA_ + gB_;                                                          \
    w  += wA_ + wB_;                                                          \
    GQN = __int_as_float(bpN_) - (cA_ + cB_);                                 \
  } while (0)

// ---------------- Kernel B: pipelined chunked backward scan ----------------
// grid 256 (batch), block 128 = 2 waves. wave 0: s-chain (c=1), wave 1: e-chain.
// lane (0..63) = vocab id v for gf/w;  q = lane&31 = chunk position for solve.
__global__ void __launch_bounds__(128, 1) scan_kernel(const int* __restrict__ seq,
                                                      const float* __restrict__ tabs,
                                                      float* __restrict__ rbuf) {
    const int b    = blockIdx.x;
    const int tid  = threadIdx.x;        // 0..127
    const int m    = tid >> 6;           // wave id == chain id
    const int lane = tid & 63;           // vocab id v
    const int q    = lane & 31;          // chunk position

    __shared__ float gt [2 * 64 * 65];   // Gram rows padded to 65
    __shared__ float hsh[2 * 64 * 32];   // h tables [m][v][j]
    __shared__ int   seq_raw[2052];      // [0] = dummy token for p = -1
    int* seq_sh = seq_raw + 1;

    // ---- stage (one-time) ----
    for (int i = tid; i < 8192; i += 128) {
        const int mm = i >> 12, v = (i >> 6) & 63, ww = i & 63;
        gt[mm * 4160 + v * 65 + ww] = tabs[16384 + i];
    }
    for (int i = tid; i < 1024; i += 128)
        ((float4*)hsh)[i] = ((const float4*)(tabs + 4096))[i];
    if (tid == 0) seq_raw[0] = 0;
    {
        const int4* s4 = (const int4*)(seq + b * L_SEQ);
        for (int i = tid; i < 512; i += 128) {
            int4 vv = s4[i];
            seq_sh[i * 4 + 0] = vv.x; seq_sh[i * 4 + 1] = vv.y;
            seq_sh[i * 4 + 2] = vv.z; seq_sh[i * 4 + 3] = vv.w;
        }
    }
    __syncthreads();

    // ---- init: u = k_tokL  =>  gf_v = G[v][tokL];  w = vocab-space r ----
    const int   tokL = seq_sh[NPOS];
    const int   mBase = m * 4160;
    const int   rowV  = mBase + lane * 65;
    const float invL  = 1.0f / (float)L_SEQ;
    const bool  mF    = (m != 0);
    const float cfs   = mF ? invL : 0.0f;

    float gf = gt[rowV + tokL];
    float w  = 0.f;

    // ---- pipeline prologue ----
    int   pkA[8], pkB[8];
    int   tqA, tqB;
    float aWA[TCH], aWB[TCH];
    float gqA, gqB;

    LOADTOK(0, pkA, tqA);
    LOADTOK(1, pkB, tqB);
    PREPAW(0, pkA, tqA, aWA);
    gqA = __int_as_float(__builtin_amdgcn_ds_bpermute(tqA << 2, __float_as_int(gf)));

    // ---- main loop: 2 chunks per iteration (bank rotation A<->B) ----
    for (int ci = 0; ci < NCH; ci += 2) {
        if (__all(fabsf(gf) < 1e-6f)) break;   // residual-based exit (per wave)
        BODY(ci,     pkA, tqA, aWA, gqA,  pkB, tqB, aWB, gqB);
        BODY(ci + 1, pkB, tqB, aWB, gqB,  pkA, tqA, aWA, gqA);
    }

    // ---- final: r_q = sum_v w_v * h[v][q] ----
    float r = 0.f;
    #pragma unroll 8
    for (int v = 0; v < 64; ++v) {
        const float wv = rdlane(w, v);
        r = fmaf(wv, hsh[(m * 64 + v) * 32 + q], r);
    }

    if (lane < 32)
        rbuf[b * 64 + m * 32 + q] = r;   // [rs | re] = concat order
}

// ---------------- Kernel C: output projection ------------------------------
__global__ void out_kernel(const float* __restrict__ rbuf,
                           const float* __restrict__ wrp, const float* __restrict__ brp,
                           const float* __restrict__ wout, const float* __restrict__ bout,
                           float* __restrict__ out) {
    const int b = blockIdx.x;
    const int t = threadIdx.x;
    __shared__ float rsh[64];
    __shared__ float ysh[64];

    rsh[t] = rbuf[b * 64 + t];
    __syncthreads();

    float y = brp[t];
    #pragma unroll 8
    for (int k = 0; k < 64; ++k) y += rsh[k] * wrp[k * 64 + t];
    ysh[t] = y;
    __syncthreads();

    float o = bout[t];
    #pragma unroll 8
    for (int k = 0; k < 64; ++k) o += ysh[k] * wout[k * 64 + t];
    out[b * 64 + t] = o;
}

// ---------------- launch ----------------------------------------------------
extern "C" void kernel_launch(void* const* d_in, const int* in_sizes, int n_in,
                              void* d_out, int out_size, void* d_ws, size_t ws_size,
                              hipStream_t stream) {
    const int*   seq   = (const int*)  d_in[0];
    const float* embed = (const float*)d_in[1];
    const float* w1    = (const float*)d_in[2];
    const float* b1    = (const float*)d_in[3];
    const float* w2    = (const float*)d_in[4];
    const float* b2    = (const float*)d_in[5];
    const float* ln_g  = (const float*)d_in[6];
    const float* ln_b  = (const float*)d_in[7];
    const float* ws    = (const float*)d_in[8];
    const float* bs    = (const float*)d_in[9];
    const float* we    = (const float*)d_in[10];
    const float* be    = (const float*)d_in[11];
    const float* wrp   = (const float*)d_in[12];
    const float* brp   = (const float*)d_in[13];
    const float* wout  = (const float*)d_in[14];
    const float* bout  = (const float*)d_in[15];

    float* tabs = (float*)d_ws;              // tables + gram
    float* gout = tabs + 16384;              // gram [2][64][64]
    float* rbuf = tabs + 24576;              // r vectors [256][64]

    build_tables<<<64, 64, 0, stream>>>(embed, w1, b1, w2, b2, ln_g, ln_b,
                                        ws, bs, we, be, tabs);
    gram_kernel<<<64, 128, 0, stream>>>(tabs, gout);
    scan_kernel<<<256, 128, 0, stream>>>(seq, tabs, rbuf);
    out_kernel<<<256, 64, 0, stream>>>(rbuf, wrp, brp, wout, bout, (float*)d_out);
}

// Round 9
// 73.416 us; speedup vs baseline: 1.8836x; 1.8836x over previous
//
#include <hip/hip_runtime.h>
#include <hip/hip_bf16.h>

// DiffAlphaSplitModel: VOCAB=64, H=64, HALF=32, B=256, L=2048.
//  1) 64 distinct tokens -> per-vocab tables: k (normalized), h (raw),
//     Gram G[v][w] = k_v . k_w per chain.
//  2) DUAL-SPACE per-position recurrence (NO chunking, NO triangular solve):
//       gf_v = k_v . u   (lane = vocab v, 64-wide)
//       per position p (backward):  d = gf[t_p]        (readlane, SGPR idx)
//                                   e = c_p * d
//                                   gf -= e * G[:,t_p] (ONE v_fmac, 64-wide)
//                                   W[t_p] += e        (cmp/select, vocab hist)
//       r = sum_v W_v h_v  once at the end.
//     Tokens are wave-uniform -> scalar loads; G-column reads are 2-way
//     bank-conflict-free and prefetched 32 ahead (addresses token-only).
//     This is the EXACT reference evaluation order.
//  s-chain and e-chain in separate waves (block=128). No barriers/LDS writes
//  in the main loop.
//
// ws layout (floats):
//   [0     ..  4095] compact k [2][64][32]
//   [4096  ..  8191] compact h [2][64][32]
//   [16384 .. 24575] Gram [2][64][64]
//   [24576 .. 40959] rbuf [256][64]

#define L_SEQ 2048
#define NPOS  2047

__device__ __forceinline__ float rdlane(float v, int l) {
    return __int_as_float(__builtin_amdgcn_readlane(__float_as_int(v), l));
}

// ---------------- Kernel A: per-vocab tables -------------------------------
__global__ void build_tables(const float* __restrict__ embed,
                             const float* __restrict__ w1, const float* __restrict__ b1,
                             const float* __restrict__ w2, const float* __restrict__ b2,
                             const float* __restrict__ ln_g, const float* __restrict__ ln_b,
                             const float* __restrict__ ws, const float* __restrict__ bs,
                             const float* __restrict__ we, const float* __restrict__ be,
                             float* __restrict__ tabs) {
    const int v = blockIdx.x;
    const int t = threadIdx.x;        // 0..63
    __shared__ float sh_h[64];
    __shared__ float sh_a[128];
    __shared__ float sh_x[64];

    sh_h[t] = embed[v * 64 + t];
    __syncthreads();

    float acc0 = b1[t], acc1 = b1[t + 64];
    #pragma unroll 8
    for (int k = 0; k < 64; ++k) {
        const float hv = sh_h[k];
        acc0 += hv * w1[k * 128 + t];
        acc1 += hv * w1[k * 128 + t + 64];
    }
    sh_a[t]      = fmaxf(acc0, 0.f);
    sh_a[t + 64] = fmaxf(acc1, 0.f);
    __syncthreads();

    float x = sh_h[t] + b2[t];
    #pragma unroll 8
    for (int k = 0; k < 128; ++k) x += sh_a[k] * w2[k * 64 + t];

    float mu = x;
    for (int m = 1; m <= 32; m <<= 1) mu += __shfl_xor(mu, m);
    mu *= (1.f / 64.f);
    const float dx = x - mu;
    float var = dx * dx;
    for (int m = 1; m <= 32; m <<= 1) var += __shfl_xor(var, m);
    var *= (1.f / 64.f);
    const float hln = dx * rsqrtf(var + 1e-5f) * ln_g[t] + ln_b[t];
    sh_x[t] = hln;
    __syncthreads();

    const int j   = t & 31;
    const int mem = t >> 5;
    const float* W  = mem ? we : ws;
    const float* Bv = mem ? be : bs;
    float p = Bv[j];
    #pragma unroll 8
    for (int k = 0; k < 64; ++k) p += sh_x[k] * W[k * 32 + j];

    float nn = p * p;
    for (int m = 1; m <= 16; m <<= 1) nn += __shfl_xor(nn, m);
    const float kn = p / fmaxf(sqrtf(nn), 1e-12f);

    tabs[(mem * 64 + v) * 32 + j]        = kn;   // normalized key
    tabs[4096 + (mem * 64 + v) * 32 + j] = p;    // raw projection
}

// ---------------- Kernel A2: Gram tables -----------------------------------
__global__ void gram_kernel(const float* __restrict__ tabs, float* __restrict__ gout) {
    const int v  = blockIdx.x;
    const int tt = threadIdx.x;          // 0..127
    const int m  = tt >> 6, w = tt & 63;
    __shared__ float kv[64];
    if (tt < 64) kv[tt] = tabs[((tt >> 5) * 64 + v) * 32 + (tt & 31)];
    __syncthreads();
    const float* kw  = &tabs[(m * 64 + w) * 32];
    const float* kvm = &kv[m * 32];
    float acc = 0.f;
    #pragma unroll 8
    for (int j = 0; j < 32; ++j) acc += kvm[j] * kw[j];
    gout[m * 4096 + v * 64 + w] = acc;
}

// ---------------- Kernel B: per-position dual-space scan -------------------
// grid 256 (batch), block 128 = 2 waves. wave 0: s-chain (c=1), wave 1: e-chain.
// lane (0..63) = vocab id v for gf / W.
__global__ void __launch_bounds__(128, 1) scan_kernel(const int* __restrict__ seq,
                                                      const float* __restrict__ tabs,
                                                      float* __restrict__ rbuf) {
    const int b    = blockIdx.x;
    const int tid  = threadIdx.x;        // 0..127
    const int m    = tid >> 6;           // wave id == chain id
    const int lane = tid & 63;           // vocab id v
    const int q    = lane & 31;

    __shared__ float gt [2 * 64 * 65];   // Gram rows padded to 65
    __shared__ float hsh[2 * 64 * 32];   // h tables [m][v][j]

    // ---- stage (one-time) ----
    for (int i = tid; i < 8192; i += 128) {
        const int mm = i >> 12, v = (i >> 6) & 63, ww = i & 63;
        gt[mm * 4160 + v * 65 + ww] = tabs[16384 + i];
    }
    for (int i = tid; i < 1024; i += 128)
        ((float4*)hsh)[i] = ((const float4*)(tabs + 4096))[i];
    __syncthreads();

    const int*  srow  = seq + b * L_SEQ;        // uniform base -> scalar loads
    const int   rowV  = m * 4160 + lane * 65;   // per-lane G row base
    const float invL  = 1.0f / (float)L_SEQ;
    const bool  mF    = (m != 0);
    const float invLe = mF ? invL : 0.0f;       // c step (0 for s-chain)

    // init: u = k_tokL  =>  gf_v = G[v][tokL]
    const int tokL = srow[NPOS];
    float gf = gt[rowV + tokL];
    float W  = 0.f;

    // ---- partial top block: positions 2046 .. 2016 (31 positions) ----
    {
        int tk[31]; float cg[31];
        #pragma unroll
        for (int j = 0; j < 31; ++j) tk[j] = srow[2016 + j];
        #pragma unroll
        for (int j = 0; j < 31; ++j) cg[j] = gt[rowV + tk[j]];
        __builtin_amdgcn_sched_barrier(0);
        const float cb = mF ? (float)(2016 + 1) * invL : 1.0f;
        #pragma unroll
        for (int j = 30; j >= 0; --j) {
            const float d = rdlane(gf, tk[j]);
            const float c = cb + (float)j * invLe;
            const float e = c * d;
            gf = fmaf(-e, cg[j], gf);
            W += (lane == tk[j]) ? e : 0.f;
        }
    }

    // ---- main blocks: pb = 1984, 1952, ..., 0  (63 blocks x 32 positions) ----
    for (int pb = 1984; pb >= 0; pb -= 32) {
        if (__all(fabsf(gf) < 1e-6f)) break;    // residual-based exit (per wave)

        int tk[32]; float cg[32];
        #pragma unroll
        for (int j = 0; j < 32; ++j) tk[j] = srow[pb + j];
        #pragma unroll
        for (int j = 0; j < 32; ++j) cg[j] = gt[rowV + tk[j]];
        __builtin_amdgcn_sched_barrier(0);

        const float cb = mF ? (float)(pb + 1) * invL : 1.0f;
        #pragma unroll
        for (int j = 31; j >= 0; --j) {
            const float d = rdlane(gf, tk[j]);
            const float c = cb + (float)j * invLe;
            const float e = c * d;
            gf = fmaf(-e, cg[j], gf);
            W += (lane == tk[j]) ? e : 0.f;
        }
    }

    // ---- final: r_q = sum_v W_v * h[v][q] ----
    float r = 0.f;
    #pragma unroll 8
    for (int v = 0; v < 64; ++v) {
        const float wv = rdlane(W, v);
        r = fmaf(wv, hsh[(m * 64 + v) * 32 + q], r);
    }

    if (lane < 32)
        rbuf[b * 64 + m * 32 + q] = r;   // [rs | re] = concat order
}

// ---------------- Kernel C: output projection ------------------------------
__global__ void out_kernel(const float* __restrict__ rbuf,
                           const float* __restrict__ wrp, const float* __restrict__ brp,
                           const float* __restrict__ wout, const float* __restrict__ bout,
                           float* __restrict__ out) {
    const int b = blockIdx.x;
    const int t = threadIdx.x;
    __shared__ float rsh[64];
    __shared__ float ysh[64];

    rsh[t] = rbuf[b * 64 + t];
    __syncthreads();

    float y = brp[t];
    #pragma unroll 8
    for (int k = 0; k < 64; ++k) y += rsh[k] * wrp[k * 64 + t];
    ysh[t] = y;
    __syncthreads();

    float o = bout[t];
    #pragma unroll 8
    for (int k = 0; k < 64; ++k) o += ysh[k] * wout[k * 64 + t];
    out[b * 64 + t] = o;
}

// ---------------- launch ----------------------------------------------------
extern "C" void kernel_launch(void* const* d_in, const int* in_sizes, int n_in,
                              void* d_out, int out_size, void* d_ws, size_t ws_size,
                              hipStream_t stream) {
    const int*   seq   = (const int*)  d_in[0];
    const float* embed = (const float*)d_in[1];
    const float* w1    = (const float*)d_in[2];
    const float* b1    = (const float*)d_in[3];
    const float* w2    = (const float*)d_in[4];
    const float* b2    = (const float*)d_in[5];
    const float* ln_g  = (const float*)d_in[6];
    const float* ln_b  = (const float*)d_in[7];
    const float* ws    = (const float*)d_in[8];
    const float* bs    = (const float*)d_in[9];
    const float* we    = (const float*)d_in[10];
    const float* be    = (const float*)d_in[11];
    const float* wrp   = (const float*)d_in[12];
    const float* brp   = (const float*)d_in[13];
    const float* wout  = (const float*)d_in[14];
    const float* bout  = (const float*)d_in[15];

    float* tabs = (float*)d_ws;              // tables + gram
    float* gout = tabs + 16384;              // gram [2][64][64]
    float* rbuf = tabs + 24576;              // r vectors [256][64]

    build_tables<<<64, 64, 0, stream>>>(embed, w1, b1, w2, b2, ln_g, ln_b,
                                        ws, bs, we, be, tabs);
    gram_kernel<<<64, 128, 0, stream>>>(tabs, gout);
    scan_kernel<<<256, 128, 0, stream>>>(seq, tabs, rbuf);
    out_kernel<<<256, 64, 0, stream>>>(rbuf, wrp, brp, wout, bout, (float*)d_out);
}